// Round 1
// baseline (6910.769 us; speedup 1.0000x reference)
//
#include <hip/hip_runtime.h>
#include <hip/hip_bf16.h>
#include <math.h>

#define NN   6000
#define NIB  1200
#define NMAXI 80
#define NAVGI 30

// float(np.sqrt(np.pi))
#define SQRT_PI_F 1.7724538509055160273f

__device__ __forceinline__ float erfcx_ref(float y) {
  // mirrors reference: clip, small/large branches, negative reflection
  y = fminf(fmaxf(y, -9.0f), 25.0f);
  float a   = fabsf(y);
  float a_s = fminf(a, 5.0f);
  float fsm = expf(a_s * a_s) * erfcf(a_s);
  float a_l = fmaxf(a, 5.0f);
  float flg = (1.0f / (SQRT_PI_F * a_l)) * (1.0f - 0.5f / (a_l * a_l));
  float f   = (a <= 5.0f) ? fsm : flg;
  return (y >= 0.0f) ? f : 2.0f * expf(y * y) - f;
}

__device__ __forceinline__ unsigned short f2bf(float f) {
  unsigned u = __float_as_uint(f);
  unsigned r = 0x7FFFu + ((u >> 16) & 1u);
  return (unsigned short)((u + r) >> 16);
}

__global__ __launch_bounds__(256) void init_kernel(
    const float* __restrict__ contrast, const float* __restrict__ grat,
    const float* __restrict__ pref, float* __restrict__ r0,
    float* __restrict__ meanv, float* __restrict__ ctab,
    float* __restrict__ qn, float* __restrict__ qw,
    unsigned* __restrict__ conv)
{
  int t = blockIdx.x * 256 + threadIdx.x;
  if (t < NN) {
    r0[t] = 0.0f;
    // thetas = linspace(0, pi-0.01, 6000); table of cos(2*theta)-1
    double th = (3.141592653589793 - 0.01) * (double)t / 5999.0;
    ctab[t] = cosf(2.0f * (float)th) - 1.0f;
    // input_mean = contrast*20*exp((cos(d*pi/90)-1)/(4*(pi/180*30)^2))
    float d  = grat[0] - pref[t];
    float cg = (cosf(d * 3.14159265358979323846f / 90.0f) - 1.0f) / 1.0966227112321508f;
    meanv[t] = contrast[0] * 20.0f * expf(cg);
  }
  if (t < NMAXI) conv[t] = 0u;
  // 64-pt Gauss-Legendre nodes/weights via Newton on Legendre recurrence (fp64)
  if (blockIdx.x == 0 && threadIdx.x < 64) {
    int m = threadIdx.x;
    double x = cos(3.141592653589793 * (m + 0.75) / 64.5);
    double p0, p1, dp = 1.0;
    for (int it = 0; it < 60; ++it) {
      p0 = 1.0; p1 = x;
      for (int k = 2; k <= 64; ++k) {
        double p2 = ((2.0 * k - 1.0) * x * p1 - (k - 1.0) * p0) / (double)k;
        p0 = p1; p1 = p2;
      }
      dp = 64.0 * (x * p1 - p0) / (x * x - 1.0);
      double step = p1 / dp;
      x -= step;
      if (fabs(step) < 1e-15) break;
    }
    p0 = 1.0; p1 = x;
    for (int k = 2; k <= 64; ++k) {
      double p2 = ((2.0 * k - 1.0) * x * p1 - (k - 1.0) * p0) / (double)k;
      p0 = p1; p1 = p2;
    }
    dp = 64.0 * (x * p1 - p0) / (x * x - 1.0);
    double wgt = 2.0 / ((1.0 - x * x) * dp * dp);
    qn[63 - m] = (float)x;   // ascending order (order irrelevant to the sum)
    qw[63 - m] = (float)wgt;
  }
}

// BF==0: fp32 W; BF==1: bf16 W
template <int BF>
__global__ __launch_bounds__(256) void genw_kernel(
    const float* __restrict__ hyper, const float* __restrict__ randu,
    const float* __restrict__ ctab, float* __restrict__ Wf,
    unsigned short* __restrict__ Wh)
{
  const int i  = blockIdx.x;
  const int ri = (i < NIB) ? 1 : 0;
  // conn = ri + 2*(j<NIB); conn_rolled = ri + 2*(idx<NIB)
  const float eA = hyper[0 + ri], eB = hyper[2 + ri];   // eff_p
  const float pA = hyper[4 + ri], pB = hyper[6 + ri];   // prob_p
  const float c  = 0.017453292519943295f;               // fp32(pi/180)
  const float wA = c * hyper[8 + ri], wB = c * hyper[10 + ri];
  const float dA = 4.0f * (wA * wA), dB = 4.0f * (wB * wB);
  const float* urow = randu + (size_t)i * NN;

  for (int j4 = threadIdx.x * 4; j4 < NN; j4 += 1024) {
    float4 uv = *reinterpret_cast<const float4*>(urow + j4);
    float us[4] = {uv.x, uv.y, uv.z, uv.w};
    float res[4];
#pragma unroll
    for (int q = 0; q < 4; ++q) {
      int j   = j4 + q;
      int idx = j - i; idx += (idx < 0) ? NN : 0;
      float ct   = ctab[idx];
      float eff  = (j   < NIB) ? eB : eA;
      float prob = (j   < NIB) ? pB : pA;
      float den  = (idx < NIB) ? dB : dA;
      float Z  = expf(ct / den);
      float tt = 32.0f * (prob * Z - us[q]);
      res[q] = eff / (1.0f + expf(-tt));
    }
    if (BF == 0) {
      *reinterpret_cast<float4*>(Wf + (size_t)i * NN + j4) =
          make_float4(res[0], res[1], res[2], res[3]);
    } else {
      uint2 pk;
      pk.x = (unsigned)f2bf(res[0]) | ((unsigned)f2bf(res[1]) << 16);
      pk.y = (unsigned)f2bf(res[2]) | ((unsigned)f2bf(res[3]) << 16);
      *reinterpret_cast<uint2*>(Wh + (size_t)i * NN + j4) = pk;
    }
  }
}

// MODE: 0 = fp32 W from ws, 1 = bf16 W from ws, 2 = recompute W on the fly
template <int MODE>
__global__ __launch_bounds__(256) void iter_kernel(
    const float* __restrict__ Wf, const unsigned short* __restrict__ Wh,
    const float* __restrict__ rin, float* __restrict__ rout,
    const float* __restrict__ meanv, const float* __restrict__ qn,
    const float* __restrict__ qw, unsigned* __restrict__ convslot,
    const float* __restrict__ hyper, const float* __restrict__ randu,
    const float* __restrict__ ctab)
{
  const int lane = threadIdx.x & 63;
  const int row  = (blockIdx.x << 2) + (threadIdx.x >> 6);  // one wave per row

  float eA = 0, eB = 0, pA = 0, pB = 0, dA = 0, dB = 0;
  if (MODE == 2) {
    const int ri = (row < NIB) ? 1 : 0;
    eA = hyper[0 + ri]; eB = hyper[2 + ri];
    pA = hyper[4 + ri]; pB = hyper[6 + ri];
    const float c = 0.017453292519943295f;
    float wA = c * hyper[8 + ri], wB = c * hyper[10 + ri];
    dA = 4.0f * (wA * wA); dB = 4.0f * (wB * wB);
  }

  const float* wrowf          = Wf + (size_t)row * NN;
  const unsigned short* wrowh = Wh + (size_t)row * NN;
  const float* urow           = randu + (size_t)row * NN;

  float mu = 0.0f, var = 0.0f;

  auto accum = [&](int j) {
    const float4 rv = *reinterpret_cast<const float4*>(rin + j);
    float w0, w1, w2, w3;
    if constexpr (MODE == 0) {
      const float4 wv = *reinterpret_cast<const float4*>(wrowf + j);
      w0 = wv.x; w1 = wv.y; w2 = wv.z; w3 = wv.w;
    } else if constexpr (MODE == 1) {
      const uint2 hv = *reinterpret_cast<const uint2*>(wrowh + j);
      w0 = __uint_as_float(hv.x << 16);
      w1 = __uint_as_float(hv.x & 0xFFFF0000u);
      w2 = __uint_as_float(hv.y << 16);
      w3 = __uint_as_float(hv.y & 0xFFFF0000u);
    } else {
      const float4 uv = *reinterpret_cast<const float4*>(urow + j);
      float us[4] = {uv.x, uv.y, uv.z, uv.w};
      float wr[4];
#pragma unroll
      for (int q = 0; q < 4; ++q) {
        int jj  = j + q;
        int idx = jj - row; idx += (idx < 0) ? NN : 0;
        float ct   = ctab[idx];
        float eff  = (jj  < NIB) ? eB : eA;
        float prob = (jj  < NIB) ? pB : pA;
        float den  = (idx < NIB) ? dB : dA;
        float Z  = expf(ct / den);
        float tt = 32.0f * (prob * Z - us[q]);
        wr[q] = eff / (1.0f + expf(-tt));
      }
      w0 = wr[0]; w1 = wr[1]; w2 = wr[2]; w3 = wr[3];
    }
    mu  += w0 * rv.x + w1 * rv.y + w2 * rv.z + w3 * rv.w;
    var += w0 * w0 * rv.x + w1 * w1 * rv.y + w2 * w2 * rv.z + w3 * w3 * rv.w;
  };

  // 6000 = 23*256 + 112 ; 64 lanes x float4 per chunk
  for (int k = 0; k < 23; ++k) accum(k * 256 + (lane << 2));
  { const int j = 5888 + (lane << 2); if (j < NN) accum(j); }

#pragma unroll
  for (int off = 32; off > 0; off >>= 1) {
    mu  += __shfl_xor(mu, off);
    var += __shfl_xor(var, off);
  }

  mu  += meanv[row];        // TAU = 1
  var += 25.0f;             // SIG_EXT^2
  const float sig = sqrtf(var);
  const float uu = (20.0f - mu) / sig;    // (VT - mu)/sig
  const float ll = (10.0f - mu) / sig;    // (VR - mu)/sig
  const float cc = 0.5f * (uu + ll);
  const float hh = 0.5f * (uu - ll);

  // 64-pt quadrature: one node per lane
  const float x    = cc + hh * qn[lane];
  float term       = qw[lane] * erfcx_ref(-x);
#pragma unroll
  for (int off = 32; off > 0; off >>= 1) term += __shfl_xor(term, off);
  const float integ = hh * term;
  const float phiv  = 1.0f / (1.0f + SQRT_PI_F * fmaxf(integ, 0.0f));

  const float rold = rin[row];
  const float dx   = (phiv - rold) * 0.1f;   // T_INV*( )*DT
  const float rnew = rold + dx;
  if (lane == 0) {
    rout[row] = rnew;
    const float ratio = fabsf(dx) / fmaxf(1.0f, fabsf(rnew));
    atomicMax(convslot, __float_as_uint(ratio));
  }
}

__global__ __launch_bounds__(256) void final_kernel(
    const float* __restrict__ rfin, const unsigned* __restrict__ conv,
    float* __restrict__ out)
{
  int t = blockIdx.x * 256 + threadIdx.x;
  if (t < NN) out[t] = rfin[t];
  if (t == 6000) {
    float s = 0.0f;
    for (int k = NMAXI - NAVGI; k < NMAXI; ++k)
      s += (__uint_as_float(conv[k]) < 1e-5f) ? 1.0f : 0.0f;
    out[NN] = s / 30.0f;
  }
}

extern "C" void kernel_launch(void* const* d_in, const int* in_sizes, int n_in,
                              void* d_out, int out_size, void* d_ws, size_t ws_size,
                              hipStream_t stream) {
  const float* hyper    = (const float*)d_in[0];  // [3][4]
  const float* contrast = (const float*)d_in[1];  // [1]
  const float* grat     = (const float*)d_in[2];  // [1]
  const float* pref     = (const float*)d_in[3];  // [6000]
  const float* randu    = (const float*)d_in[4];  // [6000*6000]
  float* out = (float*)d_out;

  char* ws = (char*)d_ws;
  float*    r0   = (float*)(ws + 0);        // 6000 f
  float*    r1   = (float*)(ws + 24000);    // 6000 f
  float*    mn   = (float*)(ws + 48000);    // 6000 f
  float*    ctab = (float*)(ws + 72000);    // 6000 f
  float*    qn   = (float*)(ws + 96000);    // 64 f
  float*    qw   = (float*)(ws + 96256);    // 64 f
  unsigned* conv = (unsigned*)(ws + 96512); // 80 u32
  const size_t smallBytes = 131072;
  float*          Wf = (float*)(ws + smallBytes);
  unsigned short* Wh = (unsigned short*)(ws + smallBytes);

  const size_t WNE = (size_t)NN * NN;
  int mode = 2;
  if (ws_size >= smallBytes + WNE * 4)      mode = 0;  // fp32 W cached (144 MB)
  else if (ws_size >= smallBytes + WNE * 2) mode = 1;  // bf16 W cached (72 MB)

  init_kernel<<<24, 256, 0, stream>>>(contrast, grat, pref, r0, mn, ctab, qn, qw, conv);
  if (mode == 0)
    genw_kernel<0><<<NN, 256, 0, stream>>>(hyper, randu, ctab, Wf, Wh);
  else if (mode == 1)
    genw_kernel<1><<<NN, 256, 0, stream>>>(hyper, randu, ctab, Wf, Wh);

  float* rb[2] = {r0, r1};
  for (int t = 0; t < NMAXI; ++t) {
    const float* rin = rb[t & 1];
    float*       rou = rb[(t + 1) & 1];
    if (mode == 0)
      iter_kernel<0><<<1500, 256, 0, stream>>>(Wf, Wh, rin, rou, mn, qn, qw,
                                               conv + t, hyper, randu, ctab);
    else if (mode == 1)
      iter_kernel<1><<<1500, 256, 0, stream>>>(Wf, Wh, rin, rou, mn, qn, qw,
                                               conv + t, hyper, randu, ctab);
    else
      iter_kernel<2><<<1500, 256, 0, stream>>>(Wf, Wh, rin, rou, mn, qn, qw,
                                               conv + t, hyper, randu, ctab);
  }
  final_kernel<<<24, 256, 0, stream>>>(r0, conv, out);
}

// Round 2
// 6080.975 us; speedup vs baseline: 1.1365x; 1.1365x over previous
//
#include <hip/hip_runtime.h>
#include <hip/hip_bf16.h>
#include <math.h>

#define NN   6000
#define NIB  1200
#define NMAXI 80
#define NAVGI 30

// float(np.sqrt(np.pi))
#define SQRT_PI_F 1.7724538509055160273f

__device__ __forceinline__ float erfcx_ref(float y) {
  // mirrors reference: clip, small/large branches, negative reflection
  y = fminf(fmaxf(y, -9.0f), 25.0f);
  float a   = fabsf(y);
  float a_s = fminf(a, 5.0f);
  float fsm = expf(a_s * a_s) * erfcf(a_s);
  float a_l = fmaxf(a, 5.0f);
  float flg = (1.0f / (SQRT_PI_F * a_l)) * (1.0f - 0.5f / (a_l * a_l));
  float f   = (a <= 5.0f) ? fsm : flg;
  return (y >= 0.0f) ? f : 2.0f * expf(y * y) - f;
}

__device__ __forceinline__ unsigned short f2bf(float f) {
  unsigned u = __float_as_uint(f);
  unsigned r = 0x7FFFu + ((u >> 16) & 1u);
  return (unsigned short)((u + r) >> 16);
}

__global__ __launch_bounds__(256) void init_kernel(
    const float* __restrict__ contrast, const float* __restrict__ grat,
    const float* __restrict__ pref, float* __restrict__ r0,
    float* __restrict__ meanv, float* __restrict__ ctab,
    float* __restrict__ qn, float* __restrict__ qw,
    unsigned* __restrict__ conv)
{
  int t = blockIdx.x * 256 + threadIdx.x;
  if (t < NN) {
    r0[t] = 0.0f;
    // thetas = linspace(0, pi-0.01, 6000); table of cos(2*theta)-1
    double th = (3.141592653589793 - 0.01) * (double)t / 5999.0;
    ctab[t] = cosf(2.0f * (float)th) - 1.0f;
    // input_mean = contrast*20*exp((cos(d*pi/90)-1)/(4*(pi/180*30)^2))
    float d  = grat[0] - pref[t];
    float cg = (cosf(d * 3.14159265358979323846f / 90.0f) - 1.0f) / 1.0966227112321508f;
    meanv[t] = contrast[0] * 20.0f * expf(cg);
  }
  if (t < NMAXI) conv[t] = 0u;
  // 64-pt Gauss-Legendre nodes/weights via Newton on Legendre recurrence (fp64)
  if (blockIdx.x == 0 && threadIdx.x < 64) {
    int m = threadIdx.x;
    double x = cos(3.141592653589793 * (m + 0.75) / 64.5);
    double p0, p1, dp = 1.0;
    for (int it = 0; it < 60; ++it) {
      p0 = 1.0; p1 = x;
      for (int k = 2; k <= 64; ++k) {
        double p2 = ((2.0 * k - 1.0) * x * p1 - (k - 1.0) * p0) / (double)k;
        p0 = p1; p1 = p2;
      }
      dp = 64.0 * (x * p1 - p0) / (x * x - 1.0);
      double step = p1 / dp;
      x -= step;
      if (fabs(step) < 1e-15) break;
    }
    p0 = 1.0; p1 = x;
    for (int k = 2; k <= 64; ++k) {
      double p2 = ((2.0 * k - 1.0) * x * p1 - (k - 1.0) * p0) / (double)k;
      p0 = p1; p1 = p2;
    }
    dp = 64.0 * (x * p1 - p0) / (x * x - 1.0);
    double wgt = 2.0 / ((1.0 - x * x) * dp * dp);
    qn[63 - m] = (float)x;   // ascending order (order irrelevant to the sum)
    qw[63 - m] = (float)wgt;
  }
}

// BF==0: fp32 W; BF==1: bf16 W
template <int BF>
__global__ __launch_bounds__(256) void genw_kernel(
    const float* __restrict__ hyper, const float* __restrict__ randu,
    const float* __restrict__ ctab, float* __restrict__ Wf,
    unsigned short* __restrict__ Wh)
{
  const int i  = blockIdx.x;
  const int ri = (i < NIB) ? 1 : 0;
  // conn = ri + 2*(j<NIB); conn_rolled = ri + 2*(idx<NIB)
  const float eA = hyper[0 + ri], eB = hyper[2 + ri];   // eff_p
  const float pA = hyper[4 + ri], pB = hyper[6 + ri];   // prob_p
  const float c  = 0.017453292519943295f;               // fp32(pi/180)
  const float wA = c * hyper[8 + ri], wB = c * hyper[10 + ri];
  const float dA = 4.0f * (wA * wA), dB = 4.0f * (wB * wB);
  const float* urow = randu + (size_t)i * NN;

  for (int j4 = threadIdx.x * 4; j4 < NN; j4 += 1024) {
    float4 uv = *reinterpret_cast<const float4*>(urow + j4);
    float us[4] = {uv.x, uv.y, uv.z, uv.w};
    float res[4];
#pragma unroll
    for (int q = 0; q < 4; ++q) {
      int j   = j4 + q;
      int idx = j - i; idx += (idx < 0) ? NN : 0;
      float ct   = ctab[idx];
      float eff  = (j   < NIB) ? eB : eA;
      float prob = (j   < NIB) ? pB : pA;
      float den  = (idx < NIB) ? dB : dA;
      float Z  = expf(ct / den);
      float tt = 32.0f * (prob * Z - us[q]);
      res[q] = eff / (1.0f + expf(-tt));
    }
    if (BF == 0) {
      *reinterpret_cast<float4*>(Wf + (size_t)i * NN + j4) =
          make_float4(res[0], res[1], res[2], res[3]);
    } else {
      uint2 pk;
      pk.x = (unsigned)f2bf(res[0]) | ((unsigned)f2bf(res[1]) << 16);
      pk.y = (unsigned)f2bf(res[2]) | ((unsigned)f2bf(res[3]) << 16);
      *reinterpret_cast<uint2*>(Wh + (size_t)i * NN + j4) = pk;
    }
  }
}

// MODE: 0 = fp32 W from ws, 1 = bf16 W from ws, 2 = recompute W on the fly
// One block (256 threads, 4 waves) per row. Chunks loaded fully unrolled for
// memory-level parallelism; cross-wave reduce in LDS; wave 0 does quadrature.
template <int MODE>
__global__ __launch_bounds__(256) void iter_kernel(
    const float* __restrict__ Wf, const unsigned short* __restrict__ Wh,
    const float* __restrict__ rin, float* __restrict__ rout,
    const float* __restrict__ meanv, const float* __restrict__ qn,
    const float* __restrict__ qw, unsigned* __restrict__ convslot,
    const float* __restrict__ hyper, const float* __restrict__ randu,
    const float* __restrict__ ctab)
{
  const int row   = blockIdx.x;
  const int tid   = threadIdx.x;
  const int lane  = tid & 63;
  const int wvid  = tid >> 6;

  __shared__ float smu[4], svar[4];

  float mu = 0.0f, var = 0.0f;

  if constexpr (MODE == 0) {
    const float* wrow = Wf + (size_t)row * NN;
    float4 w[6], r4[6];
    bool   have[6];
#pragma unroll
    for (int k = 0; k < 6; ++k) {
      const int j = (tid << 2) + (k << 10);
      have[k] = (j < NN);
      if (have[k]) {
        w[k]  = *reinterpret_cast<const float4*>(wrow + j);
        r4[k] = *reinterpret_cast<const float4*>(rin + j);
      }
    }
#pragma unroll
    for (int k = 0; k < 6; ++k) {
      if (have[k]) {
        mu  += w[k].x * r4[k].x + w[k].y * r4[k].y
             + w[k].z * r4[k].z + w[k].w * r4[k].w;
        var += w[k].x * w[k].x * r4[k].x + w[k].y * w[k].y * r4[k].y
             + w[k].z * w[k].z * r4[k].z + w[k].w * w[k].w * r4[k].w;
      }
    }
  } else if constexpr (MODE == 1) {
    const unsigned short* wrow = Wh + (size_t)row * NN;
    uint2  h[6];
    float4 r4[6];
    bool   have[6];
#pragma unroll
    for (int k = 0; k < 6; ++k) {
      const int j = (tid << 2) + (k << 10);
      have[k] = (j < NN);
      if (have[k]) {
        h[k]  = *reinterpret_cast<const uint2*>(wrow + j);
        r4[k] = *reinterpret_cast<const float4*>(rin + j);
      }
    }
#pragma unroll
    for (int k = 0; k < 6; ++k) {
      if (have[k]) {
        const float w0 = __uint_as_float(h[k].x << 16);
        const float w1 = __uint_as_float(h[k].x & 0xFFFF0000u);
        const float w2 = __uint_as_float(h[k].y << 16);
        const float w3 = __uint_as_float(h[k].y & 0xFFFF0000u);
        mu  += w0 * r4[k].x + w1 * r4[k].y + w2 * r4[k].z + w3 * r4[k].w;
        var += w0 * w0 * r4[k].x + w1 * w1 * r4[k].y
             + w2 * w2 * r4[k].z + w3 * w3 * r4[k].w;
      }
    }
  } else {
    // fallback: recompute W on the fly
    const int ri = (row < NIB) ? 1 : 0;
    const float eA = hyper[0 + ri], eB = hyper[2 + ri];
    const float pA = hyper[4 + ri], pB = hyper[6 + ri];
    const float c  = 0.017453292519943295f;
    const float wA = c * hyper[8 + ri], wB = c * hyper[10 + ri];
    const float dA = 4.0f * (wA * wA), dB = 4.0f * (wB * wB);
    const float* urow = randu + (size_t)row * NN;
    for (int j4 = tid * 4; j4 < NN; j4 += 1024) {
      const float4 uv = *reinterpret_cast<const float4*>(urow + j4);
      const float4 rv = *reinterpret_cast<const float4*>(rin + j4);
      const float us[4] = {uv.x, uv.y, uv.z, uv.w};
      const float rs[4] = {rv.x, rv.y, rv.z, rv.w};
#pragma unroll
      for (int q = 0; q < 4; ++q) {
        const int jj  = j4 + q;
        int idx = jj - row; idx += (idx < 0) ? NN : 0;
        const float ct   = ctab[idx];
        const float eff  = (jj  < NIB) ? eB : eA;
        const float prob = (jj  < NIB) ? pB : pA;
        const float den  = (idx < NIB) ? dB : dA;
        const float Z  = expf(ct / den);
        const float tt = 32.0f * (prob * Z - us[q]);
        const float w  = eff / (1.0f + expf(-tt));
        mu  += w * rs[q];
        var += w * w * rs[q];
      }
    }
  }

#pragma unroll
  for (int off = 32; off > 0; off >>= 1) {
    mu  += __shfl_xor(mu, off);
    var += __shfl_xor(var, off);
  }
  if (lane == 0) { smu[wvid] = mu; svar[wvid] = var; }
  __syncthreads();

  if (tid < 64) {
    mu  = smu[0]  + smu[1]  + smu[2]  + smu[3];
    var = svar[0] + svar[1] + svar[2] + svar[3];

    mu  += meanv[row];        // TAU = 1
    var += 25.0f;             // SIG_EXT^2
    const float sig = sqrtf(var);
    const float uu = (20.0f - mu) / sig;    // (VT - mu)/sig
    const float ll = (10.0f - mu) / sig;    // (VR - mu)/sig
    const float cc = 0.5f * (uu + ll);
    const float hh = 0.5f * (uu - ll);

    // 64-pt quadrature: one node per lane
    const float x = cc + hh * qn[lane];
    float term    = qw[lane] * erfcx_ref(-x);
#pragma unroll
    for (int off = 32; off > 0; off >>= 1) term += __shfl_xor(term, off);
    const float integ = hh * term;
    const float phiv  = 1.0f / (1.0f + SQRT_PI_F * fmaxf(integ, 0.0f));

    const float rold = rin[row];
    const float dx   = (phiv - rold) * 0.1f;   // T_INV*( )*DT
    const float rnew = rold + dx;
    if (lane == 0) {
      rout[row] = rnew;
      const float ratio = fabsf(dx) / fmaxf(1.0f, fabsf(rnew));
      atomicMax(convslot, __float_as_uint(ratio));
    }
  }
}

__global__ __launch_bounds__(256) void final_kernel(
    const float* __restrict__ rfin, const unsigned* __restrict__ conv,
    float* __restrict__ out)
{
  int t = blockIdx.x * 256 + threadIdx.x;
  if (t < NN) out[t] = rfin[t];
  if (t == 6000) {
    float s = 0.0f;
    for (int k = NMAXI - NAVGI; k < NMAXI; ++k)
      s += (__uint_as_float(conv[k]) < 1e-5f) ? 1.0f : 0.0f;
    out[NN] = s / 30.0f;
  }
}

extern "C" void kernel_launch(void* const* d_in, const int* in_sizes, int n_in,
                              void* d_out, int out_size, void* d_ws, size_t ws_size,
                              hipStream_t stream) {
  const float* hyper    = (const float*)d_in[0];  // [3][4]
  const float* contrast = (const float*)d_in[1];  // [1]
  const float* grat     = (const float*)d_in[2];  // [1]
  const float* pref     = (const float*)d_in[3];  // [6000]
  const float* randu    = (const float*)d_in[4];  // [6000*6000]
  float* out = (float*)d_out;

  char* ws = (char*)d_ws;
  float*    r0   = (float*)(ws + 0);        // 6000 f
  float*    r1   = (float*)(ws + 24000);    // 6000 f
  float*    mn   = (float*)(ws + 48000);    // 6000 f
  float*    ctab = (float*)(ws + 72000);    // 6000 f
  float*    qn   = (float*)(ws + 96000);    // 64 f
  float*    qw   = (float*)(ws + 96256);    // 64 f
  unsigned* conv = (unsigned*)(ws + 96512); // 80 u32
  const size_t smallBytes = 131072;
  float*          Wf = (float*)(ws + smallBytes);
  unsigned short* Wh = (unsigned short*)(ws + smallBytes);

  const size_t WNE = (size_t)NN * NN;
  int mode = 2;
  if (ws_size >= smallBytes + WNE * 4)      mode = 0;  // fp32 W cached (144 MB)
  else if (ws_size >= smallBytes + WNE * 2) mode = 1;  // bf16 W cached (72 MB)

  init_kernel<<<24, 256, 0, stream>>>(contrast, grat, pref, r0, mn, ctab, qn, qw, conv);
  if (mode == 0)
    genw_kernel<0><<<NN, 256, 0, stream>>>(hyper, randu, ctab, Wf, Wh);
  else if (mode == 1)
    genw_kernel<1><<<NN, 256, 0, stream>>>(hyper, randu, ctab, Wf, Wh);

  float* rb[2] = {r0, r1};
  for (int t = 0; t < NMAXI; ++t) {
    const float* rin = rb[t & 1];
    float*       rou = rb[(t + 1) & 1];
    if (mode == 0)
      iter_kernel<0><<<NN, 256, 0, stream>>>(Wf, Wh, rin, rou, mn, qn, qw,
                                             conv + t, hyper, randu, ctab);
    else if (mode == 1)
      iter_kernel<1><<<NN, 256, 0, stream>>>(Wf, Wh, rin, rou, mn, qn, qw,
                                             conv + t, hyper, randu, ctab);
    else
      iter_kernel<2><<<NN, 256, 0, stream>>>(Wf, Wh, rin, rou, mn, qn, qw,
                                             conv + t, hyper, randu, ctab);
  }
  final_kernel<<<24, 256, 0, stream>>>(r0, conv, out);
}

// Round 3
// 5571.410 us; speedup vs baseline: 1.2404x; 1.0915x over previous
//
#include <hip/hip_runtime.h>
#include <hip/hip_fp16.h>
#include <hip/hip_cooperative_groups.h>
#include <math.h>

namespace cg = cooperative_groups;

#define NN    6000
#define NPAD  6144
#define NIB   1200
#define NMAXI 80
#define NAVGI 30
#define NBLK  500
#define NTHR  768   // 12 waves; one wave per row; 500*12 = 6000 rows

// float(np.sqrt(np.pi))
#define SQRT_PI_F 1.7724538509055160273f

__device__ __forceinline__ float erfcx_ref(float y) {
  // mirrors reference: clip, small/large branches, negative reflection
  y = fminf(fmaxf(y, -9.0f), 25.0f);
  float a   = fabsf(y);
  float a_s = fminf(a, 5.0f);
  float fsm = expf(a_s * a_s) * erfcf(a_s);
  float a_l = fmaxf(a, 5.0f);
  float flg = (1.0f / (SQRT_PI_F * a_l)) * (1.0f - 0.5f / (a_l * a_l));
  float f   = (a <= 5.0f) ? fsm : flg;
  return (y >= 0.0f) ? f : 2.0f * expf(y * y) - f;
}

__global__ __launch_bounds__(256) void init_kernel(
    const float* __restrict__ contrast, const float* __restrict__ grat,
    const float* __restrict__ pref, float* __restrict__ g0,
    float* __restrict__ g1, float* __restrict__ meanv,
    float* __restrict__ ctab, float* __restrict__ qn, float* __restrict__ qw,
    unsigned* __restrict__ conv)
{
  int t = blockIdx.x * 256 + threadIdx.x;
  if (t < NPAD) { g0[t] = 0.0f; g1[t] = 0.0f; }   // r0 = 0, pads = 0
  if (t < NN) {
    double th = (3.141592653589793 - 0.01) * (double)t / 5999.0;
    ctab[t] = cosf(2.0f * (float)th) - 1.0f;
    float d  = grat[0] - pref[t];
    float cg = (cosf(d * 3.14159265358979323846f / 90.0f) - 1.0f) / 1.0966227112321508f;
    meanv[t] = contrast[0] * 20.0f * expf(cg);
  }
  if (t < NMAXI) conv[t] = 0u;
  // 64-pt Gauss-Legendre nodes/weights via Newton on Legendre recurrence (fp64)
  if (blockIdx.x == 0 && threadIdx.x < 64) {
    int m = threadIdx.x;
    double x = cos(3.141592653589793 * (m + 0.75) / 64.5);
    double p0, p1, dp = 1.0;
    for (int it = 0; it < 60; ++it) {
      p0 = 1.0; p1 = x;
      for (int k = 2; k <= 64; ++k) {
        double p2 = ((2.0 * k - 1.0) * x * p1 - (k - 1.0) * p0) / (double)k;
        p0 = p1; p1 = p2;
      }
      dp = 64.0 * (x * p1 - p0) / (x * x - 1.0);
      double step = p1 / dp;
      x -= step;
      if (fabs(step) < 1e-15) break;
    }
    p0 = 1.0; p1 = x;
    for (int k = 2; k <= 64; ++k) {
      double p2 = ((2.0 * k - 1.0) * x * p1 - (k - 1.0) * p0) / (double)k;
      p0 = p1; p1 = p2;
    }
    dp = 64.0 * (x * p1 - p0) / (x * x - 1.0);
    double wgt = 2.0 / ((1.0 - x * x) * dp * dp);
    qn[63 - m] = (float)x;
    qw[63 - m] = (float)wgt;
  }
}

// Persistent cooperative kernel: W lives in registers as fp16, 80 iterations
// with grid-wide sync. One wave per row.
__global__ __launch_bounds__(NTHR, 6) void solve_kernel(
    const float* __restrict__ hyper, const float* __restrict__ randu,
    const float* __restrict__ ctab, const float* __restrict__ meanv,
    const float* __restrict__ qn, const float* __restrict__ qw,
    float* __restrict__ g0, float* __restrict__ g1,
    float* __restrict__ blkmax, float* __restrict__ out)
{
  cg::grid_group grid = cg::this_grid();

  const int tid  = threadIdx.x;
  const int lane = tid & 63;
  const int wv   = tid >> 6;
  const int row  = blockIdx.x * 12 + wv;

  __shared__ float rls[NPAD];
  __shared__ float wmax[12];
  __shared__ float sflag[NAVGI];

  // per-lane quadrature constants, per-row feedforward mean
  const float qnl = qn[lane];
  const float qwl = qw[lane];
  const float mean_row = meanv[row];

  // ---- generate this row's W into registers (fp16 x4 per uint2) ----
  uint2 Wreg[24];
  {
    const int ri = (row < NIB) ? 1 : 0;
    const float eA = hyper[0 + ri], eB = hyper[2 + ri];
    const float pA = hyper[4 + ri], pB = hyper[6 + ri];
    const float c  = 0.017453292519943295f;   // fp32(pi/180)
    const float wA = c * hyper[8 + ri], wB = c * hyper[10 + ri];
    const float dA = 4.0f * (wA * wA), dB = 4.0f * (wB * wB);
    const float* urow = randu + (size_t)row * NN;
#pragma unroll
    for (int k = 0; k < 24; ++k) {
      const int j0 = k * 256 + (lane << 2);
      float w[4] = {0.0f, 0.0f, 0.0f, 0.0f};
      if (j0 + 3 < NN) {
        const float4 uv = *reinterpret_cast<const float4*>(urow + j0);
        const float us[4] = {uv.x, uv.y, uv.z, uv.w};
#pragma unroll
        for (int q = 0; q < 4; ++q) {
          const int j = j0 + q;
          int idx = j - row; idx += (idx < 0) ? NN : 0;
          const float ct   = ctab[idx];
          const float eff  = (j   < NIB) ? eB : eA;
          const float prob = (j   < NIB) ? pB : pA;
          const float den  = (idx < NIB) ? dB : dA;
          const float Z  = expf(ct / den);
          const float tt = 32.0f * (prob * Z - us[q]);
          w[q] = eff / (1.0f + expf(-tt));
        }
      }
      const __half2 h01 = __floats2half2_rn(w[0], w[1]);
      const __half2 h23 = __floats2half2_rn(w[2], w[3]);
      Wreg[k].x = *reinterpret_cast<const unsigned*>(&h01);
      Wreg[k].y = *reinterpret_cast<const unsigned*>(&h23);
    }
  }

  // ---- fixed-point iteration ----
  for (int t = 0; t < NMAXI; ++t) {
    const float* rcur = (t & 1) ? g1 : g0;
    float*       rnxt = (t & 1) ? g0 : g1;

    // stage r into LDS (6144 floats = 1536 float4; 768 threads x 2)
    {
      const float4* rc4 = reinterpret_cast<const float4*>(rcur);
      float4* ld4 = reinterpret_cast<float4*>(rls);
      const float4 s0 = rc4[tid];
      const float4 s1 = rc4[tid + NTHR];
      ld4[tid]        = s0;
      ld4[tid + NTHR] = s1;
    }
    __syncthreads();

    // fused W.r and (W*W).r
    float mu = 0.0f, var = 0.0f;
#pragma unroll
    for (int k = 0; k < 24; ++k) {
      const float4 rv = *reinterpret_cast<const float4*>(&rls[k * 256 + (lane << 2)]);
      const __half2 h01 = *reinterpret_cast<const __half2*>(&Wreg[k].x);
      const __half2 h23 = *reinterpret_cast<const __half2*>(&Wreg[k].y);
      const float w0 = __low2float(h01), w1 = __high2float(h01);
      const float w2 = __low2float(h23), w3 = __high2float(h23);
      const float t0 = w0 * rv.x, t1 = w1 * rv.y, t2 = w2 * rv.z, t3 = w3 * rv.w;
      mu  += (t0 + t1) + (t2 + t3);
      var = fmaf(t0, w0, fmaf(t1, w1, fmaf(t2, w2, fmaf(t3, w3, var))));
    }
#pragma unroll
    for (int off = 32; off > 0; off >>= 1) {
      mu  += __shfl_xor(mu, off);
      var += __shfl_xor(var, off);
    }

    mu  += mean_row;          // TAU = 1
    var += 25.0f;             // SIG_EXT^2
    const float sig = sqrtf(var);
    const float uu = (20.0f - mu) / sig;
    const float ll = (10.0f - mu) / sig;
    const float cc = 0.5f * (uu + ll);
    const float hh = 0.5f * (uu - ll);

    // 64-pt quadrature, one node per lane
    const float x = cc + hh * qnl;
    float term    = qwl * erfcx_ref(-x);
#pragma unroll
    for (int off = 32; off > 0; off >>= 1) term += __shfl_xor(term, off);
    const float integ = hh * term;
    const float phiv  = 1.0f / (1.0f + SQRT_PI_F * fmaxf(integ, 0.0f));

    const float rold = rls[row];
    const float dx   = (phiv - rold) * 0.1f;
    const float rnew = rold + dx;
    const float ratio = fabsf(dx) / fmaxf(1.0f, fabsf(rnew));

    if (lane == 0) {
      if (t == NMAXI - 1) out[row] = rnew;
      else                rnxt[row] = rnew;
      wmax[wv] = ratio;
    }
    __syncthreads();
    if (tid == 0) {
      float m = wmax[0];
#pragma unroll
      for (int q = 1; q < 12; ++q) m = fmaxf(m, wmax[q]);
      blkmax[(size_t)t * NBLK + blockIdx.x] = m;
    }
    grid.sync();
  }

  // ---- convergence epilogue: block 0 reduces blkmax over [50,80) ----
  if (blockIdx.x == 0) {
#pragma unroll
    for (int s = 0; s < 3; ++s) {
      const int t = 50 + wv + 12 * s;
      if (t < NMAXI) {
        float m = 0.0f;   // ratios are >= 0
        for (int p = lane; p < NBLK; p += 64)
          m = fmaxf(m, blkmax[(size_t)t * NBLK + p]);
#pragma unroll
        for (int off = 32; off > 0; off >>= 1)
          m = fmaxf(m, __shfl_xor(m, off));
        if (lane == 0) sflag[t - 50] = (m < 1e-5f) ? 1.0f : 0.0f;
      }
    }
    __syncthreads();
    if (tid == 0) {
      float s = 0.0f;
#pragma unroll
      for (int q = 0; q < NAVGI; ++q) s += sflag[q];
      out[NN] = s / 30.0f;
    }
  }
}

// ---------------- fallback path (round-2 structure, fp32 W in ws) ----------
__global__ __launch_bounds__(256) void genw_kernel(
    const float* __restrict__ hyper, const float* __restrict__ randu,
    const float* __restrict__ ctab, float* __restrict__ Wf)
{
  const int i  = blockIdx.x;
  const int ri = (i < NIB) ? 1 : 0;
  const float eA = hyper[0 + ri], eB = hyper[2 + ri];
  const float pA = hyper[4 + ri], pB = hyper[6 + ri];
  const float c  = 0.017453292519943295f;
  const float wA = c * hyper[8 + ri], wB = c * hyper[10 + ri];
  const float dA = 4.0f * (wA * wA), dB = 4.0f * (wB * wB);
  const float* urow = randu + (size_t)i * NN;
  for (int j4 = threadIdx.x * 4; j4 < NN; j4 += 1024) {
    float4 uv = *reinterpret_cast<const float4*>(urow + j4);
    float us[4] = {uv.x, uv.y, uv.z, uv.w};
    float res[4];
#pragma unroll
    for (int q = 0; q < 4; ++q) {
      int j   = j4 + q;
      int idx = j - i; idx += (idx < 0) ? NN : 0;
      float ct   = ctab[idx];
      float eff  = (j   < NIB) ? eB : eA;
      float prob = (j   < NIB) ? pB : pA;
      float den  = (idx < NIB) ? dB : dA;
      float Z  = expf(ct / den);
      float tt = 32.0f * (prob * Z - us[q]);
      res[q] = eff / (1.0f + expf(-tt));
    }
    *reinterpret_cast<float4*>(Wf + (size_t)i * NN + j4) =
        make_float4(res[0], res[1], res[2], res[3]);
  }
}

__global__ __launch_bounds__(256) void iter_kernel(
    const float* __restrict__ Wf, const float* __restrict__ rin,
    float* __restrict__ rout, const float* __restrict__ meanv,
    const float* __restrict__ qn, const float* __restrict__ qw,
    unsigned* __restrict__ convslot)
{
  const int row  = blockIdx.x;
  const int tid  = threadIdx.x;
  const int lane = tid & 63;
  const int wvid = tid >> 6;
  __shared__ float smu[4], svar[4];
  float mu = 0.0f, var = 0.0f;
  const float* wrow = Wf + (size_t)row * NN;
  float4 w[6], r4[6]; bool have[6];
#pragma unroll
  for (int k = 0; k < 6; ++k) {
    const int j = (tid << 2) + (k << 10);
    have[k] = (j < NN);
    if (have[k]) {
      w[k]  = *reinterpret_cast<const float4*>(wrow + j);
      r4[k] = *reinterpret_cast<const float4*>(rin + j);
    }
  }
#pragma unroll
  for (int k = 0; k < 6; ++k) if (have[k]) {
    mu  += w[k].x * r4[k].x + w[k].y * r4[k].y + w[k].z * r4[k].z + w[k].w * r4[k].w;
    var += w[k].x * w[k].x * r4[k].x + w[k].y * w[k].y * r4[k].y
         + w[k].z * w[k].z * r4[k].z + w[k].w * w[k].w * r4[k].w;
  }
#pragma unroll
  for (int off = 32; off > 0; off >>= 1) {
    mu  += __shfl_xor(mu, off);
    var += __shfl_xor(var, off);
  }
  if (lane == 0) { smu[wvid] = mu; svar[wvid] = var; }
  __syncthreads();
  if (tid < 64) {
    mu  = smu[0] + smu[1] + smu[2] + smu[3];
    var = svar[0] + svar[1] + svar[2] + svar[3];
    mu += meanv[row]; var += 25.0f;
    const float sig = sqrtf(var);
    const float uu = (20.0f - mu) / sig;
    const float ll = (10.0f - mu) / sig;
    const float cc = 0.5f * (uu + ll);
    const float hh = 0.5f * (uu - ll);
    const float x = cc + hh * qn[lane];
    float term    = qw[lane] * erfcx_ref(-x);
#pragma unroll
    for (int off = 32; off > 0; off >>= 1) term += __shfl_xor(term, off);
    const float integ = hh * term;
    const float phiv  = 1.0f / (1.0f + SQRT_PI_F * fmaxf(integ, 0.0f));
    const float rold = rin[row];
    const float dx   = (phiv - rold) * 0.1f;
    const float rnew = rold + dx;
    if (lane == 0) {
      rout[row] = rnew;
      const float ratio = fabsf(dx) / fmaxf(1.0f, fabsf(rnew));
      atomicMax(convslot, __float_as_uint(ratio));
    }
  }
}

__global__ __launch_bounds__(256) void final_kernel(
    const float* __restrict__ rfin, const unsigned* __restrict__ conv,
    float* __restrict__ out)
{
  int t = blockIdx.x * 256 + threadIdx.x;
  if (t < NN) out[t] = rfin[t];
  if (t == 6000) {
    float s = 0.0f;
    for (int k = NMAXI - NAVGI; k < NMAXI; ++k)
      s += (__uint_as_float(conv[k]) < 1e-5f) ? 1.0f : 0.0f;
    out[NN] = s / 30.0f;
  }
}

extern "C" void kernel_launch(void* const* d_in, const int* in_sizes, int n_in,
                              void* d_out, int out_size, void* d_ws, size_t ws_size,
                              hipStream_t stream) {
  const float* hyper    = (const float*)d_in[0];
  const float* contrast = (const float*)d_in[1];
  const float* grat     = (const float*)d_in[2];
  const float* pref     = (const float*)d_in[3];
  const float* randu    = (const float*)d_in[4];
  float* out = (float*)d_out;

  char* ws = (char*)d_ws;
  float*    g0     = (float*)(ws + 0);       // 6144 f (r buf A + pad)
  float*    g1     = (float*)(ws + 24576);   // 6144 f (r buf B + pad)
  float*    mn     = (float*)(ws + 49152);   // 6000 f
  float*    ctab   = (float*)(ws + 73152);   // 6000 f
  float*    qn     = (float*)(ws + 97152);   // 64 f
  float*    qw     = (float*)(ws + 97408);   // 64 f
  unsigned* conv   = (unsigned*)(ws + 97664);// 80 u32 (fallback)
  float*    blkmax = (float*)(ws + 98304);   // 80*500 f
  float*    Wf     = (float*)(ws + 262144);  // fallback fp32 W

  init_kernel<<<24, 256, 0, stream>>>(contrast, grat, pref, g0, g1, mn, ctab, qn, qw, conv);

  // cooperative persistent kernel: W in registers (fp16), 80 internal iters
  {
    const float* a_hyper = hyper;  const float* a_randu = randu;
    const float* a_ctab  = ctab;   const float* a_mn    = mn;
    const float* a_qn    = qn;     const float* a_qw    = qw;
    float* a_g0 = g0; float* a_g1 = g1; float* a_bm = blkmax; float* a_out = out;
    void* args[10] = {&a_hyper, &a_randu, &a_ctab, &a_mn, &a_qn, &a_qw,
                      &a_g0, &a_g1, &a_bm, &a_out};
    hipError_t err = hipLaunchCooperativeKernel(
        (const void*)solve_kernel, dim3(NBLK), dim3(NTHR), args, 0, stream);
    if (err == hipSuccess) return;
  }

  // fallback: round-2 structure
  genw_kernel<<<NN, 256, 0, stream>>>(hyper, randu, ctab, Wf);
  float* rb[2] = {g0, g1};
  for (int t = 0; t < NMAXI; ++t) {
    const float* rin = rb[t & 1];
    float*       rou = rb[(t + 1) & 1];
    iter_kernel<<<NN, 256, 0, stream>>>(Wf, rin, rou, mn, qn, qw, conv + t);
  }
  final_kernel<<<24, 256, 0, stream>>>(rb[0], conv, out);
}

// Round 4
// 2767.814 us; speedup vs baseline: 2.4968x; 2.0129x over previous
//
#include <hip/hip_runtime.h>
#include <hip/hip_fp16.h>
#include <hip/hip_cooperative_groups.h>
#include <math.h>

namespace cg = cooperative_groups;

#define NN    6000
#define NPAD  6144
#define NIB   1200
#define NMAXI 80
#define NAVGI 30
#define NBLK  250
#define NTHR  768   // 12 waves/block, 2 rows per wave -> 24 rows/block, 250 blocks

// float(np.sqrt(np.pi))
#define SQRT_PI_F 1.7724538509055160273f

typedef _Float16 half2_t __attribute__((ext_vector_type(2)));

__device__ __forceinline__ float erfcx_ref(float y) {
  // mirrors reference: clip, small/large branches, negative reflection
  y = fminf(fmaxf(y, -9.0f), 25.0f);
  float a   = fabsf(y);
  float a_s = fminf(a, 5.0f);
  float fsm = expf(a_s * a_s) * erfcf(a_s);
  float a_l = fmaxf(a, 5.0f);
  float flg = (1.0f / (SQRT_PI_F * a_l)) * (1.0f - 0.5f / (a_l * a_l));
  float f   = (a <= 5.0f) ? fsm : flg;
  return (y >= 0.0f) ? f : 2.0f * expf(y * y) - f;
}

__device__ __forceinline__ float dot2acc(unsigned w, unsigned r, float acc) {
#if defined(__has_builtin) && __has_builtin(__builtin_amdgcn_fdot2)
  return __builtin_amdgcn_fdot2(__builtin_bit_cast(half2_t, w),
                                __builtin_bit_cast(half2_t, r), acc, false);
#else
  half2_t wh = __builtin_bit_cast(half2_t, w);
  half2_t rh = __builtin_bit_cast(half2_t, r);
  return acc + (float)wh.x * (float)rh.x + (float)wh.y * (float)rh.y;
#endif
}

__device__ __forceinline__ unsigned pksq(unsigned w) {
  half2_t wh = __builtin_bit_cast(half2_t, w);
  half2_t s  = wh * wh;                 // v_pk_mul_f16
  return __builtin_bit_cast(unsigned, s);
}

__global__ __launch_bounds__(256) void init_kernel(
    const float* __restrict__ contrast, const float* __restrict__ grat,
    const float* __restrict__ pref, float* __restrict__ g0,
    float* __restrict__ g1, float* __restrict__ meanv,
    float* __restrict__ ctab, float* __restrict__ qn, float* __restrict__ qw,
    unsigned* __restrict__ conv)
{
  int t = blockIdx.x * 256 + threadIdx.x;
  if (t < NPAD) { g0[t] = 0.0f; g1[t] = 0.0f; }   // r0 = 0, pads = 0
  if (t < NN) {
    double th = (3.141592653589793 - 0.01) * (double)t / 5999.0;
    ctab[t] = cosf(2.0f * (float)th) - 1.0f;
    float d  = grat[0] - pref[t];
    float cg = (cosf(d * 3.14159265358979323846f / 90.0f) - 1.0f) / 1.0966227112321508f;
    meanv[t] = contrast[0] * 20.0f * expf(cg);
  }
  if (t < NMAXI) conv[t] = 0u;
  // 64-pt Gauss-Legendre nodes/weights via Newton on Legendre recurrence (fp64)
  if (blockIdx.x == 0 && threadIdx.x < 64) {
    int m = threadIdx.x;
    double x = cos(3.141592653589793 * (m + 0.75) / 64.5);
    double p0, p1, dp = 1.0;
    for (int it = 0; it < 60; ++it) {
      p0 = 1.0; p1 = x;
      for (int k = 2; k <= 64; ++k) {
        double p2 = ((2.0 * k - 1.0) * x * p1 - (k - 1.0) * p0) / (double)k;
        p0 = p1; p1 = p2;
      }
      dp = 64.0 * (x * p1 - p0) / (x * x - 1.0);
      double step = p1 / dp;
      x -= step;
      if (fabs(step) < 1e-15) break;
    }
    p0 = 1.0; p1 = x;
    for (int k = 2; k <= 64; ++k) {
      double p2 = ((2.0 * k - 1.0) * x * p1 - (k - 1.0) * p0) / (double)k;
      p0 = p1; p1 = p2;
    }
    dp = 64.0 * (x * p1 - p0) / (x * x - 1.0);
    double wgt = 2.0 / ((1.0 - x * x) * dp * dp);
    qn[63 - m] = (float)x;
    qw[63 - m] = (float)wgt;
  }
}

// Persistent cooperative kernel. 250 blocks x 768 threads = 1 block/CU,
// 3 waves/EU -> VGPR cap 170. Each wave owns TWO rows; W (fp16) lives in
// 96 VGPRs per thread. r staged in LDS as fp16; dot via v_dot2_f32_f16.
__global__ __launch_bounds__(NTHR, 3) void solve_kernel(
    const float* __restrict__ hyper, const float* __restrict__ randu,
    const float* __restrict__ ctab, const float* __restrict__ meanv,
    const float* __restrict__ qn, const float* __restrict__ qw,
    float* __restrict__ g0, float* __restrict__ g1,
    float* __restrict__ blkmax, float* __restrict__ out)
{
  cg::grid_group grid = cg::this_grid();

  const int tid  = threadIdx.x;
  const int lane = tid & 63;
  const int wv   = tid >> 6;
  const int rowA = blockIdx.x * 24 + wv * 2;
  const int rowB = rowA + 1;

  __shared__ float    ctabs[NN];
  __shared__ unsigned rh[NPAD / 2];   // fp16 r, packed pairs
  __shared__ float    wmax[12];
  __shared__ float    sflag[NAVGI];

  // stage ctab into LDS (one-time)
  {
    const float4* c4 = reinterpret_cast<const float4*>(ctab);
    float4* l4 = reinterpret_cast<float4*>(ctabs);
    for (int i = tid; i < NN / 4; i += NTHR) l4[i] = c4[i];
  }
  __syncthreads();

  const float qnl = qn[lane];
  const float qwl = qw[lane];
  const float meanA = meanv[rowA];
  const float meanB = meanv[rowB];

  // ---- generate both rows' W into registers (fp16, packed 2/uint) ----
  uint2 WA[24], WB[24];
  {
#pragma unroll
    for (int rr = 0; rr < 2; ++rr) {
      const int row = rr ? rowB : rowA;
      uint2* Wreg = rr ? WB : WA;
      const int ri = (row < NIB) ? 1 : 0;
      const float eA = hyper[0 + ri], eB = hyper[2 + ri];
      const float pA = hyper[4 + ri], pB = hyper[6 + ri];
      const float c  = 0.017453292519943295f;   // fp32(pi/180)
      const float wdA = c * hyper[8 + ri], wdB = c * hyper[10 + ri];
      const float dA = 4.0f * (wdA * wdA), dB = 4.0f * (wdB * wdB);
      const float* urow = randu + (size_t)row * NN;
#pragma unroll
      for (int k = 0; k < 24; ++k) {
        const int j0 = k * 256 + (lane << 2);
        float w[4] = {0.0f, 0.0f, 0.0f, 0.0f};
        if (j0 + 3 < NN) {
          const float4 uv = *reinterpret_cast<const float4*>(urow + j0);
          const float us[4] = {uv.x, uv.y, uv.z, uv.w};
#pragma unroll
          for (int q = 0; q < 4; ++q) {
            const int j = j0 + q;
            int idx = j - row; idx += (idx < 0) ? NN : 0;
            const float ct   = ctabs[idx];
            const float eff  = (j   < NIB) ? eB : eA;
            const float prob = (j   < NIB) ? pB : pA;
            const float den  = (idx < NIB) ? dB : dA;
            const float Z  = expf(ct / den);
            const float tt = 32.0f * (prob * Z - us[q]);
            w[q] = eff / (1.0f + expf(-tt));
          }
        }
        half2_t h01; h01.x = (_Float16)w[0]; h01.y = (_Float16)w[1];
        half2_t h23; h23.x = (_Float16)w[2]; h23.y = (_Float16)w[3];
        Wreg[k].x = __builtin_bit_cast(unsigned, h01);
        Wreg[k].y = __builtin_bit_cast(unsigned, h23);
      }
    }
  }

  // ---- fixed-point iteration ----
  for (int t = 0; t < NMAXI; ++t) {
    const float* rcur = (t & 1) ? g1 : g0;
    float*       rnxt = (t & 1) ? g0 : g1;

    // stage r (fp32 global -> fp16 LDS): 8 floats per thread
    {
      const float4* rc4 = reinterpret_cast<const float4*>(rcur);
      const float4 s0 = rc4[tid * 2];
      const float4 s1 = rc4[tid * 2 + 1];
      half2_t a, b, c2, d2;
      a.x  = (_Float16)s0.x; a.y  = (_Float16)s0.y;
      b.x  = (_Float16)s0.z; b.y  = (_Float16)s0.w;
      c2.x = (_Float16)s1.x; c2.y = (_Float16)s1.y;
      d2.x = (_Float16)s1.z; d2.y = (_Float16)s1.w;
      uint4 pk;
      pk.x = __builtin_bit_cast(unsigned, a);
      pk.y = __builtin_bit_cast(unsigned, b);
      pk.z = __builtin_bit_cast(unsigned, c2);
      pk.w = __builtin_bit_cast(unsigned, d2);
      reinterpret_cast<uint4*>(rh)[tid] = pk;
    }
    __syncthreads();

    // fused W.r and (W*W).r for both rows, via v_dot2_f32_f16
    float muA = 0.0f, varA = 0.0f, muB = 0.0f, varB = 0.0f;
#pragma unroll
    for (int k = 0; k < 24; ++k) {
      const uint2 rr = reinterpret_cast<const uint2*>(rh)[k * 64 + lane];
      muA  = dot2acc(WA[k].x, rr.x, muA);
      muA  = dot2acc(WA[k].y, rr.y, muA);
      varA = dot2acc(pksq(WA[k].x), rr.x, varA);
      varA = dot2acc(pksq(WA[k].y), rr.y, varA);
      muB  = dot2acc(WB[k].x, rr.x, muB);
      muB  = dot2acc(WB[k].y, rr.y, muB);
      varB = dot2acc(pksq(WB[k].x), rr.x, varB);
      varB = dot2acc(pksq(WB[k].y), rr.y, varB);
    }
#pragma unroll
    for (int off = 32; off > 0; off >>= 1) {
      muA  += __shfl_xor(muA, off);
      varA += __shfl_xor(varA, off);
      muB  += __shfl_xor(muB, off);
      varB += __shfl_xor(varB, off);
    }

    float ratioM = 0.0f;
#pragma unroll
    for (int rr = 0; rr < 2; ++rr) {
      const int   row  = rr ? rowB : rowA;
      float mu  = (rr ? muB : muA)  + (rr ? meanB : meanA);
      float var = (rr ? varB : varA) + 25.0f;
      const float sig = sqrtf(var);
      const float uu = (20.0f - mu) / sig;
      const float ll = (10.0f - mu) / sig;
      const float cc = 0.5f * (uu + ll);
      const float hh = 0.5f * (uu - ll);
      const float x = cc + hh * qnl;
      float term    = qwl * erfcx_ref(-x);
#pragma unroll
      for (int off = 32; off > 0; off >>= 1) term += __shfl_xor(term, off);
      const float integ = hh * term;
      const float phiv  = 1.0f / (1.0f + SQRT_PI_F * fmaxf(integ, 0.0f));

      const float rold = rcur[row];           // exact fp32 state
      const float dx   = (phiv - rold) * 0.1f;
      const float rnew = rold + dx;
      ratioM = fmaxf(ratioM, fabsf(dx) / fmaxf(1.0f, fabsf(rnew)));
      if (lane == 0) {
        if (t == NMAXI - 1) out[row] = rnew;
        else                rnxt[row] = rnew;
      }
    }
    if (lane == 0) wmax[wv] = ratioM;
    __syncthreads();
    if (tid == 0) {
      float m = wmax[0];
#pragma unroll
      for (int q = 1; q < 12; ++q) m = fmaxf(m, wmax[q]);
      blkmax[(size_t)t * NBLK + blockIdx.x] = m;
    }
    grid.sync();
  }

  // ---- convergence epilogue: block 0 reduces blkmax over [50,80) ----
  if (blockIdx.x == 0) {
#pragma unroll
    for (int s = 0; s < 3; ++s) {
      const int t = 50 + wv + 12 * s;
      if (t < NMAXI) {
        float m = 0.0f;   // ratios are >= 0
        for (int p = lane; p < NBLK; p += 64)
          m = fmaxf(m, blkmax[(size_t)t * NBLK + p]);
#pragma unroll
        for (int off = 32; off > 0; off >>= 1)
          m = fmaxf(m, __shfl_xor(m, off));
        if (lane == 0) sflag[t - 50] = (m < 1e-5f) ? 1.0f : 0.0f;
      }
    }
    __syncthreads();
    if (tid == 0) {
      float s = 0.0f;
#pragma unroll
      for (int q = 0; q < NAVGI; ++q) s += sflag[q];
      out[NN] = s / 30.0f;
    }
  }
}

// ---------------- fallback path (round-2 structure, fp32 W in ws) ----------
__global__ __launch_bounds__(256) void genw_kernel(
    const float* __restrict__ hyper, const float* __restrict__ randu,
    const float* __restrict__ ctab, float* __restrict__ Wf)
{
  const int i  = blockIdx.x;
  const int ri = (i < NIB) ? 1 : 0;
  const float eA = hyper[0 + ri], eB = hyper[2 + ri];
  const float pA = hyper[4 + ri], pB = hyper[6 + ri];
  const float c  = 0.017453292519943295f;
  const float wA = c * hyper[8 + ri], wB = c * hyper[10 + ri];
  const float dA = 4.0f * (wA * wA), dB = 4.0f * (wB * wB);
  const float* urow = randu + (size_t)i * NN;
  for (int j4 = threadIdx.x * 4; j4 < NN; j4 += 1024) {
    float4 uv = *reinterpret_cast<const float4*>(urow + j4);
    float us[4] = {uv.x, uv.y, uv.z, uv.w};
    float res[4];
#pragma unroll
    for (int q = 0; q < 4; ++q) {
      int j   = j4 + q;
      int idx = j - i; idx += (idx < 0) ? NN : 0;
      float ct   = ctab[idx];
      float eff  = (j   < NIB) ? eB : eA;
      float prob = (j   < NIB) ? pB : pA;
      float den  = (idx < NIB) ? dB : dA;
      float Z  = expf(ct / den);
      float tt = 32.0f * (prob * Z - us[q]);
      res[q] = eff / (1.0f + expf(-tt));
    }
    *reinterpret_cast<float4*>(Wf + (size_t)i * NN + j4) =
        make_float4(res[0], res[1], res[2], res[3]);
  }
}

__global__ __launch_bounds__(256) void iter_kernel(
    const float* __restrict__ Wf, const float* __restrict__ rin,
    float* __restrict__ rout, const float* __restrict__ meanv,
    const float* __restrict__ qn, const float* __restrict__ qw,
    unsigned* __restrict__ convslot)
{
  const int row  = blockIdx.x;
  const int tid  = threadIdx.x;
  const int lane = tid & 63;
  const int wvid = tid >> 6;
  __shared__ float smu[4], svar[4];
  float mu = 0.0f, var = 0.0f;
  const float* wrow = Wf + (size_t)row * NN;
  float4 w[6], r4[6]; bool have[6];
#pragma unroll
  for (int k = 0; k < 6; ++k) {
    const int j = (tid << 2) + (k << 10);
    have[k] = (j < NN);
    if (have[k]) {
      w[k]  = *reinterpret_cast<const float4*>(wrow + j);
      r4[k] = *reinterpret_cast<const float4*>(rin + j);
    }
  }
#pragma unroll
  for (int k = 0; k < 6; ++k) if (have[k]) {
    mu  += w[k].x * r4[k].x + w[k].y * r4[k].y + w[k].z * r4[k].z + w[k].w * r4[k].w;
    var += w[k].x * w[k].x * r4[k].x + w[k].y * w[k].y * r4[k].y
         + w[k].z * w[k].z * r4[k].z + w[k].w * w[k].w * r4[k].w;
  }
#pragma unroll
  for (int off = 32; off > 0; off >>= 1) {
    mu  += __shfl_xor(mu, off);
    var += __shfl_xor(var, off);
  }
  if (lane == 0) { smu[wvid] = mu; svar[wvid] = var; }
  __syncthreads();
  if (tid < 64) {
    mu  = smu[0] + smu[1] + smu[2] + smu[3];
    var = svar[0] + svar[1] + svar[2] + svar[3];
    mu += meanv[row]; var += 25.0f;
    const float sig = sqrtf(var);
    const float uu = (20.0f - mu) / sig;
    const float ll = (10.0f - mu) / sig;
    const float cc = 0.5f * (uu + ll);
    const float hh = 0.5f * (uu - ll);
    const float x = cc + hh * qn[lane];
    float term    = qw[lane] * erfcx_ref(-x);
#pragma unroll
    for (int off = 32; off > 0; off >>= 1) term += __shfl_xor(term, off);
    const float integ = hh * term;
    const float phiv  = 1.0f / (1.0f + SQRT_PI_F * fmaxf(integ, 0.0f));
    const float rold = rin[row];
    const float dx   = (phiv - rold) * 0.1f;
    const float rnew = rold + dx;
    if (lane == 0) {
      rout[row] = rnew;
      const float ratio = fabsf(dx) / fmaxf(1.0f, fabsf(rnew));
      atomicMax(convslot, __float_as_uint(ratio));
    }
  }
}

__global__ __launch_bounds__(256) void final_kernel(
    const float* __restrict__ rfin, const unsigned* __restrict__ conv,
    float* __restrict__ out)
{
  int t = blockIdx.x * 256 + threadIdx.x;
  if (t < NN) out[t] = rfin[t];
  if (t == 6000) {
    float s = 0.0f;
    for (int k = NMAXI - NAVGI; k < NMAXI; ++k)
      s += (__uint_as_float(conv[k]) < 1e-5f) ? 1.0f : 0.0f;
    out[NN] = s / 30.0f;
  }
}

extern "C" void kernel_launch(void* const* d_in, const int* in_sizes, int n_in,
                              void* d_out, int out_size, void* d_ws, size_t ws_size,
                              hipStream_t stream) {
  const float* hyper    = (const float*)d_in[0];
  const float* contrast = (const float*)d_in[1];
  const float* grat     = (const float*)d_in[2];
  const float* pref     = (const float*)d_in[3];
  const float* randu    = (const float*)d_in[4];
  float* out = (float*)d_out;

  char* ws = (char*)d_ws;
  float*    g0     = (float*)(ws + 0);       // 6144 f (r buf A + pad)
  float*    g1     = (float*)(ws + 24576);   // 6144 f (r buf B + pad)
  float*    mn     = (float*)(ws + 49152);   // 6000 f
  float*    ctab   = (float*)(ws + 73152);   // 6000 f
  float*    qn     = (float*)(ws + 97152);   // 64 f
  float*    qw     = (float*)(ws + 97408);   // 64 f
  unsigned* conv   = (unsigned*)(ws + 97664);// 80 u32 (fallback)
  float*    blkmax = (float*)(ws + 98304);   // 80*250 f
  float*    Wf     = (float*)(ws + 262144);  // fallback fp32 W

  init_kernel<<<24, 256, 0, stream>>>(contrast, grat, pref, g0, g1, mn, ctab, qn, qw, conv);

  // cooperative persistent kernel: W in registers (fp16), 80 internal iters
  {
    const float* a_hyper = hyper;  const float* a_randu = randu;
    const float* a_ctab  = ctab;   const float* a_mn    = mn;
    const float* a_qn    = qn;     const float* a_qw    = qw;
    float* a_g0 = g0; float* a_g1 = g1; float* a_bm = blkmax; float* a_out = out;
    void* args[10] = {&a_hyper, &a_randu, &a_ctab, &a_mn, &a_qn, &a_qw,
                      &a_g0, &a_g1, &a_bm, &a_out};
    hipError_t err = hipLaunchCooperativeKernel(
        (const void*)solve_kernel, dim3(NBLK), dim3(NTHR), args, 0, stream);
    if (err == hipSuccess) return;
  }

  // fallback: round-2 structure
  genw_kernel<<<NN, 256, 0, stream>>>(hyper, randu, ctab, Wf);
  float* rb[2] = {g0, g1};
  for (int t = 0; t < NMAXI; ++t) {
    const float* rin = rb[t & 1];
    float*       rou = rb[(t + 1) & 1];
    iter_kernel<<<NN, 256, 0, stream>>>(Wf, rin, rou, mn, qn, qw, conv + t);
  }
  final_kernel<<<24, 256, 0, stream>>>(rb[0], conv, out);
}